// Round 1
// baseline (9276.019 us; speedup 1.0000x reference)
//
#include <hip/hip_runtime.h>

// LSTM last-hidden + projection. B=256, T=4096, F=32, H=128, 4H=512.
// 16 WGs x 256 threads; WG g owns batches [16g, 16g+16).
// Per step: z(16x512) = [x_t | h] (16x160) @ [W;U] (160x512) via mfma 16x16x32 bf16,
// 3-product hi/lo split for ~fp16+ effective precision. Weights register-resident.

#define TT 4096
#define FF 32
#define HH 128
#define NG 512

typedef float f32x4 __attribute__((ext_vector_type(4)));
typedef short bf16x8 __attribute__((ext_vector_type(8)));

__device__ __forceinline__ short f2bf(float f) {
    unsigned u = __float_as_uint(f);
    unsigned r = (u + 0x7fffu + ((u >> 16) & 1u)) >> 16;   // RNE
    return (short)r;
}
__device__ __forceinline__ float bf2f(short s) {
    return __uint_as_float(((unsigned)(unsigned short)s) << 16);
}
__device__ __forceinline__ float sigmoid_f(float x) {
    return __builtin_amdgcn_rcpf(1.f + __expf(-x));
}
__device__ __forceinline__ float tanh_f(float x) {
    // handles saturation: exp->inf gives 1, exp->0 gives -1
    return 1.f - 2.f * __builtin_amdgcn_rcpf(__expf(2.f * x) + 1.f);
}

__global__ __launch_bounds__(256, 1)
void lstm_seq_kernel(const float* __restrict__ x,        // (B,T,F)
                     const int*   __restrict__ seq_lens, // (B)
                     const float* __restrict__ W,        // (F,4H)
                     const float* __restrict__ U,        // (H,4H)
                     const float* __restrict__ bias,     // (4H)
                     const float* __restrict__ Wf,       // (H)
                     const float* __restrict__ bfp,      // (1)
                     float* __restrict__ out)            // (B)
{
    // A-operand staging, frag-major: Ah[par][kc][lane][j] == A[m=lane&15][k=kc*32+(lane>>4)*8+j]
    __shared__ short Ah[2][5][64][8];
    __shared__ short Al[2][5][64][8];
    __shared__ float outAcc[16];
    __shared__ int smax;

    const int tid  = threadIdx.x;
    const int lane = tid & 63;
    const int w    = tid >> 6;     // wave 0..3
    const int c    = lane & 15;    // n-col within tile
    const int q    = lane >> 4;    // quad 0..3
    const int b0   = blockIdx.x * 16;

    // ---- zero LDS (h-region of parity 0 must start as h=0)
    {
        short* p0 = &Ah[0][0][0][0];
        short* p1 = &Al[0][0][0][0];
        for (int i = tid; i < 2 * 5 * 64 * 8; i += 256) { p0[i] = 0; p1[i] = 0; }
        if (tid < 16) outAcc[tid] = 0.f;
        if (tid == 0) smax = 0;
    }
    __syncthreads();

    int sl[4];
    #pragma unroll
    for (int r = 0; r < 4; ++r) sl[r] = seq_lens[b0 + q * 4 + r];
    if (tid < 16) atomicMax(&smax, seq_lens[b0 + tid]);

    // ---- register-resident weight fragments (one-time).
    // wave w -> tiles {w+4j}: j=0,1 gate i | 2,3 gate f | 4,5 gate g | 6,7 gate o
    // B-frag: lane holds B[k = kc*32 + q*8 + e][n = tile*16 + c]
    bf16x8 bh[8][5], bl[8][5];
    #pragma unroll
    for (int j = 0; j < 8; ++j) {
        const int n = (w + 4 * j) * 16 + c;
        #pragma unroll
        for (int kc = 0; kc < 5; ++kc) {
            #pragma unroll
            for (int e = 0; e < 8; ++e) {
                const int k = kc * 32 + q * 8 + e;
                float v = (k < FF) ? W[k * NG + n] : U[(k - FF) * NG + n];
                short hi = f2bf(v);
                bh[j][kc][e] = hi;
                bl[j][kc][e] = f2bf(v - bf2f(hi));
            }
        }
    }

    // per-lane bias / Wf for this lane's two hidx slots s=0,1: hc = (w+4s)*16+c
    float bi[2][4], wf[2];
    #pragma unroll
    for (int s = 0; s < 2; ++s) {
        const int hc = (w + 4 * s) * 16 + c;
        bi[s][0] = bias[hc];
        bi[s][1] = bias[HH + hc];
        bi[s][2] = bias[2 * HH + hc];
        bi[s][3] = bias[3 * HH + hc];
        wf[s] = Wf[hc];
    }

    // ---- x_0 staging: threads 0..127, xb = batch row, fgi = float4 group
    const int xb  = tid >> 3;
    const int fgi = tid & 7;
    const float* xbase = x + (size_t)(b0 + xb) * TT * FF + fgi * 4;
    const int xslot = xb + 16 * (fgi >> 1);
    const int xj    = (fgi & 1) * 4;
    if (tid < 128) {
        float4 v = *(const float4*)xbase;
        float vv[4] = {v.x, v.y, v.z, v.w};
        #pragma unroll
        for (int e = 0; e < 4; ++e) {
            short hi = f2bf(vv[e]);
            Ah[0][0][xslot][xj + e] = hi;
            Al[0][0][xslot][xj + e] = f2bf(vv[e] - bf2f(hi));
        }
    }
    __syncthreads();
    const int gmax = smax;

    float cc[2][4] = {{0.f,0.f,0.f,0.f},{0.f,0.f,0.f,0.f}};
    float hh[2][4] = {{0.f,0.f,0.f,0.f},{0.f,0.f,0.f,0.f}};

    for (int t = 0; t < gmax; ++t) {
        const int par = t & 1;
        const int p2  = par ^ 1;

        // prefetch x_{t+1} (consumed at end of iteration)
        float4 xv;
        const bool havex = (tid < 128) && (t + 1 < gmax);
        if (havex) xv = *(const float4*)(xbase + (size_t)(t + 1) * FF);

        // ---- z = A @ B, 3-product split
        f32x4 acc[8];
        #pragma unroll
        for (int j = 0; j < 8; ++j) { f32x4 z = {0.f, 0.f, 0.f, 0.f}; acc[j] = z; }
        #pragma unroll
        for (int kc = 0; kc < 5; ++kc) {
            bf16x8 ah = *(const bf16x8*)&Ah[par][kc][lane][0];
            bf16x8 al = *(const bf16x8*)&Al[par][kc][lane][0];
            #pragma unroll
            for (int j = 0; j < 8; ++j)
                acc[j] = __builtin_amdgcn_mfma_f32_16x16x32_bf16(ah, bh[j][kc], acc[j], 0, 0, 0);
            #pragma unroll
            for (int j = 0; j < 8; ++j)
                acc[j] = __builtin_amdgcn_mfma_f32_16x16x32_bf16(al, bh[j][kc], acc[j], 0, 0, 0);
            #pragma unroll
            for (int j = 0; j < 8; ++j)
                acc[j] = __builtin_amdgcn_mfma_f32_16x16x32_bf16(ah, bl[j][kc], acc[j], 0, 0, 0);
        }

        // ---- activations; C-layout: row m = q*4+r (batch), col = tile*16+c
        #pragma unroll
        for (int s = 0; s < 2; ++s) {
            const int hc = (w + 4 * s) * 16 + c;
            const int k  = 32 + hc;
            const int kc = k >> 5;
            const int jj = k & 7;
            const int sbase = 16 * ((k >> 3) & 3);
            #pragma unroll
            for (int r = 0; r < 4; ++r) {
                float zi = acc[0 + s][r] + bi[s][0];
                float zf = acc[2 + s][r] + bi[s][1];
                float zg = acc[4 + s][r] + bi[s][2];
                float zo = acc[6 + s][r] + bi[s][3];
                float gi = sigmoid_f(zi);
                float gf = sigmoid_f(zf);
                float gg = tanh_f(zg);
                float go = sigmoid_f(zo);
                float cn = gf * cc[s][r] + gi * gg;
                float hn = go * tanh_f(cn);
                const bool upd = (t < sl[r]);
                cc[s][r] = upd ? cn : cc[s][r];
                hh[s][r] = upd ? hn : hh[s][r];
                const int slot = (q * 4 + r) + sbase;
                short hbf = f2bf(hh[s][r]);
                Ah[p2][kc][slot][jj] = hbf;
                Al[p2][kc][slot][jj] = f2bf(hh[s][r] - bf2f(hbf));
            }
        }

        // ---- stage x_{t+1}
        if (havex) {
            float vv[4] = {xv.x, xv.y, xv.z, xv.w};
            #pragma unroll
            for (int e = 0; e < 4; ++e) {
                short hi = f2bf(vv[e]);
                Ah[p2][0][xslot][xj + e] = hi;
                Al[p2][0][xslot][xj + e] = f2bf(vv[e] - bf2f(hi));
            }
        }
        __syncthreads();
    }

    // ---- epilogue: out[b] = h_final[b] @ Wf + bf
    #pragma unroll
    for (int r = 0; r < 4; ++r) {
        float p = hh[0][r] * wf[0] + hh[1][r] * wf[1];
        atomicAdd(&outAcc[q * 4 + r], p);
    }
    __syncthreads();
    if (tid < 16) out[b0 + tid] = outAcc[tid] + bfp[0];
}

extern "C" void kernel_launch(void* const* d_in, const int* in_sizes, int n_in,
                              void* d_out, int out_size, void* d_ws, size_t ws_size,
                              hipStream_t stream) {
    const float* x        = (const float*)d_in[0];
    const int*   seq_lens = (const int*)d_in[1];
    const float* W        = (const float*)d_in[2];
    const float* U        = (const float*)d_in[3];
    const float* bias     = (const float*)d_in[4];
    const float* Wf       = (const float*)d_in[5];
    const float* bfp      = (const float*)d_in[6];
    float* out = (float*)d_out;

    lstm_seq_kernel<<<dim3(16), dim3(256), 0, stream>>>(x, seq_lens, W, U, bias, Wf, bfp, out);
}

// Round 2
// 6551.956 us; speedup vs baseline: 1.4158x; 1.4158x over previous
//
#include <hip/hip_runtime.h>

// LSTM last-hidden + projection. B=256, T=4096, F=32, H=128, 4H=512.
// 64 WGs x 256 threads (4 waves, 1/SIMD); WG g owns batches [4g, 4g+4) placed at
// MFMA A-rows {0,4,8,12} so the C-layout (row=q*4+r) gives every lane r=0 real data.
// Per step: z(4x512) = [x_t | h](4x160) @ [W;U](160x512) via mfma_f32_16x16x32_f16,
// 2-product split: A single fp16; B = fp16 hi + fp16 lo*2^12 (separate accumulator).
// Calibrated model: MFMA = ~19.4 cy/instr/SIMD -> 80 instr = 1552 cy; act 2 cells
// = ~280 cy; total ~2100 cy/step.

#define TT 4096
#define FF 32
#define HH 128
#define NG 512

typedef float f32x4 __attribute__((ext_vector_type(4)));
typedef _Float16 h16x8 __attribute__((ext_vector_type(8)));
typedef _Float16 h16x4 __attribute__((ext_vector_type(4)));

#define LO_SCALE 4096.0f
#define LO_INV   (1.0f/4096.0f)

__device__ __forceinline__ float sigmoid_f(float x) {
    return __builtin_amdgcn_rcpf(1.f + __expf(-x));
}
__device__ __forceinline__ float tanh_f(float x) {
    // saturates correctly: exp->inf => 1, exp->0 => -1
    return 1.f - 2.f * __builtin_amdgcn_rcpf(__expf(2.f * x) + 1.f);
}

__global__ __launch_bounds__(256, 1)
void lstm_seq_kernel(const float* __restrict__ x,        // (B,T,F)
                     const int*   __restrict__ seq_lens, // (B)
                     const float* __restrict__ W,        // (F,4H)
                     const float* __restrict__ U,        // (H,4H)
                     const float* __restrict__ bias,     // (4H)
                     const float* __restrict__ Wf,       // (H)
                     const float* __restrict__ bfp,      // (1)
                     float* __restrict__ out)            // (B)
{
    // A-operand frag-major: A[par][kc][slot][j] == A[m = slot&15][k = kc*32 + (slot>>4)*8 + j]
    __shared__ _Float16 A[2][5][64][8];
    __shared__ float outAcc[4];

    const int tid  = threadIdx.x;
    const int lane = tid & 63;
    const int w    = tid >> 6;     // wave 0..3
    const int c    = lane & 15;    // n-col within tile
    const int q    = lane >> 4;    // quad 0..3 -> this lane's batch
    const int b0   = blockIdx.x * 4;

    // zero LDS once (pad rows / x region of both parities must be 0)
    {
        _Float16* p = &A[0][0][0][0];
        for (int i = tid; i < 2 * 5 * 64 * 8; i += 256) p[i] = (_Float16)0.f;
        if (tid < 4) outAcc[tid] = 0.f;
    }

    const int sl0 = seq_lens[b0 + 0], sl1 = seq_lens[b0 + 1];
    const int sl2 = seq_lens[b0 + 2], sl3 = seq_lens[b0 + 3];
    const int gmax = max(max(sl0, sl1), max(sl2, sl3));
    const int slq  = seq_lens[b0 + q];   // this lane's batch

    // ---- register-resident weights: wave w -> tiles {w+4j}; j=0,1:i  2,3:f  4,5:g  6,7:o
    // B-frag: lane holds B[k = kc*32 + q*8 + e][n = tile*16 + c]
    h16x8 bh[8][5], bl[8][5];
    #pragma unroll
    for (int j = 0; j < 8; ++j) {
        const int n = (w + 4 * j) * 16 + c;
        #pragma unroll
        for (int kc = 0; kc < 5; ++kc) {
            #pragma unroll
            for (int e = 0; e < 8; ++e) {
                const int k = kc * 32 + q * 8 + e;
                float v = (k < FF) ? W[k * NG + n] : U[(k - FF) * NG + n];
                _Float16 hi = (_Float16)v;
                bh[j][kc][e] = hi;
                bl[j][kc][e] = (_Float16)((v - (float)hi) * LO_SCALE);
            }
        }
    }

    // per-lane bias/Wf and h-writeback coords for its 2 cells (s=0,1): hc=(w+4s)*16+c
    float bi[2][4], wf[2];
    int wkc[2], wslot[2], wj[2];
    #pragma unroll
    for (int s = 0; s < 2; ++s) {
        const int hc = (w + 4 * s) * 16 + c;
        bi[s][0] = bias[hc];
        bi[s][1] = bias[HH + hc];
        bi[s][2] = bias[2 * HH + hc];
        bi[s][3] = bias[3 * HH + hc];
        wf[s] = Wf[hc];
        const int k = FF + hc;           // K-position of this h element
        wkc[s]   = k >> 5;
        wslot[s] = ((k >> 3) & 3) * 16 + 4 * q;   // batch q lives at row 4q
        wj[s]    = k & 7;
    }

    // ---- x staging (threads 0..31): batch xb at row 4*xb, f-group xg
    const int xb = tid >> 3, xg = tid & 7;
    const float* xptr = x + (size_t)(b0 + xb) * TT * FF + xg * 4;
    const int xslot = ((xg >> 1) & 3) * 16 + 4 * xb;
    const int xj    = (xg & 1) * 4;

    if (tid < 32) {
        float4 v = *(const float4*)xptr;
        h16x4 hv = { (_Float16)v.x, (_Float16)v.y, (_Float16)v.z, (_Float16)v.w };
        *(h16x4*)&A[0][0][xslot][xj] = hv;
    }
    __syncthreads();

    float cc[2] = {0.f, 0.f}, hh[2] = {0.f, 0.f};
    const f32x4 zero4 = {0.f, 0.f, 0.f, 0.f};   // persistent zero quad (no per-step acc memset)

    for (int t = 0; t < gmax; ++t) {
        const int par = t & 1, p2 = par ^ 1;

        // prefetch x_{t+1}
        float4 xv;
        const bool havex = (tid < 32) && (t + 1 < gmax);
        if (havex) xv = *(const float4*)(xptr + (size_t)(t + 1) * FF);

        // ---- z = A @ (Bhi + Blo*2^-12): 80 MFMA/wave
        f32x4 accH[8], accL[8];
        {
            h16x8 a0 = *(const h16x8*)&A[par][0][lane][0];
            #pragma unroll
            for (int j = 0; j < 8; ++j) {
                accH[j] = __builtin_amdgcn_mfma_f32_16x16x32_f16(a0, bh[j][0], zero4, 0, 0, 0);
                accL[j] = __builtin_amdgcn_mfma_f32_16x16x32_f16(a0, bl[j][0], zero4, 0, 0, 0);
            }
        }
        #pragma unroll
        for (int kc = 1; kc < 5; ++kc) {
            h16x8 a = *(const h16x8*)&A[par][kc][lane][0];
            #pragma unroll
            for (int j = 0; j < 8; ++j) {
                accH[j] = __builtin_amdgcn_mfma_f32_16x16x32_f16(a, bh[j][kc], accH[j], 0, 0, 0);
                accL[j] = __builtin_amdgcn_mfma_f32_16x16x32_f16(a, bl[j][kc], accL[j], 0, 0, 0);
            }
        }

        // ---- activations: only r=0 is a real batch row (row 4q = batch q)
        float zs[8];
        #pragma unroll
        for (int j = 0; j < 8; ++j) zs[j] = accH[j][0] + accL[j][0] * LO_INV;

        const bool upd = (t < slq);
        #pragma unroll
        for (int s = 0; s < 2; ++s) {
            float zi = zs[0 + s] + bi[s][0];
            float zf = zs[2 + s] + bi[s][1];
            float zg = zs[4 + s] + bi[s][2];
            float zo = zs[6 + s] + bi[s][3];
            float gi = sigmoid_f(zi);
            float gf = sigmoid_f(zf);
            float gg = tanh_f(zg);
            float go = sigmoid_f(zo);
            float cn = gf * cc[s] + gi * gg;
            float hn = go * tanh_f(cn);
            cc[s] = upd ? cn : cc[s];
            hh[s] = upd ? hn : hh[s];
            A[p2][wkc[s]][wslot[s]][wj[s]] = (_Float16)hh[s];
        }

        // ---- stage x_{t+1}
        if (havex) {
            h16x4 hv = { (_Float16)xv.x, (_Float16)xv.y, (_Float16)xv.z, (_Float16)xv.w };
            *(h16x4*)&A[p2][0][xslot][xj] = hv;
        }
        __syncthreads();
    }

    // ---- epilogue: out[b] = h @ Wf + bf; reduce over c (16 lanes) then waves
    float p = hh[0] * wf[0] + hh[1] * wf[1];
    p += __shfl_down(p, 8, 16);
    p += __shfl_down(p, 4, 16);
    p += __shfl_down(p, 2, 16);
    p += __shfl_down(p, 1, 16);
    if (c == 0) atomicAdd(&outAcc[q], p);
    __syncthreads();
    if (tid < 4) out[b0 + tid] = outAcc[tid] + bfp[0];
}

extern "C" void kernel_launch(void* const* d_in, const int* in_sizes, int n_in,
                              void* d_out, int out_size, void* d_ws, size_t ws_size,
                              hipStream_t stream) {
    const float* x        = (const float*)d_in[0];
    const int*   seq_lens = (const int*)d_in[1];
    const float* W        = (const float*)d_in[2];
    const float* U        = (const float*)d_in[3];
    const float* bias     = (const float*)d_in[4];
    const float* Wf       = (const float*)d_in[5];
    const float* bfp      = (const float*)d_in[6];
    float* out = (float*)d_out;

    lstm_seq_kernel<<<dim3(64), dim3(256), 0, stream>>>(x, seq_lens, W, U, bias, Wf, bfp, out);
}

// Round 3
// 3362.202 us; speedup vs baseline: 2.7589x; 1.9487x over previous
//
#include <hip/hip_runtime.h>

// LSTM last-hidden + projection. B=256, T=4096, F=32, H=128, 4H=512.
// 64 WGs x 512 threads (8 waves = 2 waves/SIMD, to saturate the MFMA pipe:
// calibrated single-wave MFMA issue ~29cy vs ~19.4cy pipe rate).
// WG g owns batches [4g,4g+4) at MFMA A-rows {0,4,8,12} (C row = q*4+r -> r=0 real).
// Per step: z(4x512) = [x_t | h](4x160) @ [W;U](160x512), mfma_f32_16x16x32_f16,
// SINGLE fp16 product (error model from R1/R2: absmax ~2x input rounding err
// -> ~2-3e-3 vs 1.26e-2 threshold).
// Wave w owns N-tiles {w, 8+w, 16+w, 24+w} = gates {i,f,g,o} of cells hc=16w+c
// -> exactly 1 LSTM cell per lane, activations fully lane-local.

#define TT 4096
#define FF 32
#define HH 128
#define NG 512

typedef float f32x4 __attribute__((ext_vector_type(4)));
typedef _Float16 h16x8 __attribute__((ext_vector_type(8)));
typedef _Float16 h16x4 __attribute__((ext_vector_type(4)));

__device__ __forceinline__ float sigmoid_f(float x) {
    return __builtin_amdgcn_rcpf(1.f + __expf(-x));
}
__device__ __forceinline__ float tanh_f(float x) {
    // saturates correctly: exp->inf => 1, exp->0 => -1
    return 1.f - 2.f * __builtin_amdgcn_rcpf(__expf(2.f * x) + 1.f);
}

__global__ __launch_bounds__(512, 2)
void lstm_seq_kernel(const float* __restrict__ x,        // (B,T,F)
                     const int*   __restrict__ seq_lens, // (B)
                     const float* __restrict__ W,        // (F,4H)
                     const float* __restrict__ U,        // (H,4H)
                     const float* __restrict__ bias,     // (4H)
                     const float* __restrict__ Wf,       // (H)
                     const float* __restrict__ bfp,      // (1)
                     float* __restrict__ out)            // (B)
{
    // A-operand frag-major: A[par][kc][slot][j] == A[m=slot&15][k=kc*32+(slot>>4)*8+j]
    __shared__ _Float16 A[2][5][64][8];
    __shared__ float outAcc[4];

    const int tid  = threadIdx.x;
    const int lane = tid & 63;
    const int w    = tid >> 6;     // wave 0..7
    const int c    = lane & 15;    // n-col within tile
    const int q    = lane >> 4;    // quad 0..3 -> this lane's batch
    const int b0   = blockIdx.x * 4;
    const int hc   = w * 16 + c;   // this lane's LSTM cell index (0..127)

    // zero LDS once (rows !=0 mod 4 stay zero forever)
    {
        _Float16* p = &A[0][0][0][0];
        for (int i = tid; i < 2 * 5 * 64 * 8; i += 512) p[i] = (_Float16)0.f;
        if (tid < 4) outAcc[tid] = 0.f;
    }

    const int sl0 = seq_lens[b0 + 0], sl1 = seq_lens[b0 + 1];
    const int sl2 = seq_lens[b0 + 2], sl3 = seq_lens[b0 + 3];
    const int gmax = max(max(sl0, sl1), max(sl2, sl3));
    const int slq  = seq_lens[b0 + q];   // this lane's batch

    // ---- register-resident weights, single fp16 product.
    // wave w -> tiles {j*8+w}, j=0..3 = gate {i,f,g,o}; n = j*128 + hc... per-lane col c.
    // B-frag: lane holds B[k = kc*32 + q*8 + e][n = (j*8+w)*16 + c]
    h16x8 bh[4][5];
    #pragma unroll
    for (int j = 0; j < 4; ++j) {
        const int n = j * 128 + hc;
        #pragma unroll
        for (int kc = 0; kc < 5; ++kc) {
            #pragma unroll
            for (int e = 0; e < 8; ++e) {
                const int k = kc * 32 + q * 8 + e;
                float v = (k < FF) ? W[k * NG + n] : U[(k - FF) * NG + n];
                bh[j][kc][e] = (_Float16)v;
            }
        }
    }

    // per-lane bias/Wf and h-writeback coords for cell hc
    float bi[4], wfv;
    bi[0] = bias[hc];
    bi[1] = bias[HH + hc];
    bi[2] = bias[2 * HH + hc];
    bi[3] = bias[3 * HH + hc];
    wfv = Wf[hc];
    const int kk    = FF + hc;                  // K-position of this h element
    const int wkc   = kk >> 5;
    const int wslot = ((kk >> 3) & 3) * 16 + 4 * q;   // batch q lives at row 4q
    const int wj    = kk & 7;

    // ---- x staging (threads 0..31): batch xb at row 4*xb, f-group xg
    const int xb = tid >> 3, xg = tid & 7;
    const float* xptr = x + (size_t)(b0 + xb) * TT * FF + xg * 4;
    const int xslot = ((xg >> 1) & 3) * 16 + 4 * xb;
    const int xj    = (xg & 1) * 4;

    if (tid < 32) {
        float4 v = *(const float4*)xptr;
        h16x4 hv = { (_Float16)v.x, (_Float16)v.y, (_Float16)v.z, (_Float16)v.w };
        *(h16x4*)&A[0][0][xslot][xj] = hv;
    }
    __syncthreads();

    float cc = 0.f, hh = 0.f;
    const f32x4 zero4 = {0.f, 0.f, 0.f, 0.f};

    for (int t = 0; t < gmax; ++t) {
        const int par = t & 1, p2 = par ^ 1;

        // prefetch x_{t+1}
        float4 xv;
        const bool havex = (tid < 32) && (t + 1 < gmax);
        if (havex) xv = *(const float4*)(xptr + (size_t)(t + 1) * FF);

        // ---- z = A @ B: 20 MFMA/wave, 40/SIMD (2 waves interleave on the pipe)
        f32x4 acc[4];
        {
            h16x8 a0 = *(const h16x8*)&A[par][0][lane][0];
            #pragma unroll
            for (int j = 0; j < 4; ++j)
                acc[j] = __builtin_amdgcn_mfma_f32_16x16x32_f16(a0, bh[j][0], zero4, 0, 0, 0);
        }
        #pragma unroll
        for (int kc = 1; kc < 5; ++kc) {
            h16x8 a = *(const h16x8*)&A[par][kc][lane][0];
            #pragma unroll
            for (int j = 0; j < 4; ++j)
                acc[j] = __builtin_amdgcn_mfma_f32_16x16x32_f16(a, bh[j][kc], acc[j], 0, 0, 0);
        }

        // ---- activation: 1 cell/lane; C-layout row = q*4 + r, only r=0 real
        {
            float zi = acc[0][0] + bi[0];
            float zf = acc[1][0] + bi[1];
            float zg = acc[2][0] + bi[2];
            float zo = acc[3][0] + bi[3];
            float gi = sigmoid_f(zi);
            float gf = sigmoid_f(zf);
            float gg = tanh_f(zg);
            float go = sigmoid_f(zo);
            float cn = gf * cc + gi * gg;
            float hn = go * tanh_f(cn);
            const bool upd = (t < slq);
            cc = upd ? cn : cc;
            hh = upd ? hn : hh;
            A[p2][wkc][wslot][wj] = (_Float16)hh;
        }

        // ---- stage x_{t+1}
        if (havex) {
            h16x4 hv = { (_Float16)xv.x, (_Float16)xv.y, (_Float16)xv.z, (_Float16)xv.w };
            *(h16x4*)&A[p2][0][xslot][xj] = hv;
        }
        __syncthreads();
    }

    // ---- epilogue: out[b] = h @ Wf + bf; reduce over c (16 lanes) then over waves
    float p = hh * wfv;
    p += __shfl_down(p, 8, 16);
    p += __shfl_down(p, 4, 16);
    p += __shfl_down(p, 2, 16);
    p += __shfl_down(p, 1, 16);
    if (c == 0) atomicAdd(&outAcc[q], p);
    __syncthreads();
    if (tid < 4) out[b0 + tid] = outAcc[tid] + bfp[0];
}

extern "C" void kernel_launch(void* const* d_in, const int* in_sizes, int n_in,
                              void* d_out, int out_size, void* d_ws, size_t ws_size,
                              hipStream_t stream) {
    const float* x        = (const float*)d_in[0];
    const int*   seq_lens = (const int*)d_in[1];
    const float* W        = (const float*)d_in[2];
    const float* U        = (const float*)d_in[3];
    const float* bias     = (const float*)d_in[4];
    const float* Wf       = (const float*)d_in[5];
    const float* bfp      = (const float*)d_in[6];
    float* out = (float*)d_out;

    lstm_seq_kernel<<<dim3(64), dim3(512), 0, stream>>>(x, seq_lens, W, U, bias, Wf, bfp, out);
}